// Round 3
// baseline (108.115 us; speedup 1.0000x reference)
//
#include <hip/hip_runtime.h>
#include <hip/hip_bf16.h>

// B=32, T=4096, F=16, L=2047, n=8192, 256 output freqs.
// Math: s[b,t] = sum_f x[b,t,f]; r[b,tau] = sum_t s[t]*s[t+tau] (tau=0..2048)
// G[b,m] = (A[m]/16384) * exp(-2*pi*i*2047*m/4096),
// A[m] = sum_{j=0}^{2048} w_j * r[j] * cos(2*pi*m*j/4096), w_0=w_2048=1 else 2.
// OUTPUT LAYOUT PROBE: planar — Re(G) at [b*256+m], Im(G) at [8192 + b*256+m].

#define B_DIM 32
#define T_DIM 4096
#define NLAG 2049
#define THETA 1.5339807878856412e-03f   // 2*pi/4096

// ---------------- K1: s[b,t] = sum_f x[b,t,f] ----------------
__global__ __launch_bounds__(256) void ksum(const float* __restrict__ x,
                                            float* __restrict__ s) {
    int i = blockIdx.x * 256 + threadIdx.x;          // 0..131071 = b*4096+t
    const float4* xv = (const float4*)(x + (size_t)i * 16);
    float4 a = xv[0], b = xv[1], c = xv[2], d = xv[3];
    s[i] = ((a.x + a.y) + (a.z + a.w)) + ((b.x + b.y) + (b.z + b.w)) +
           ((c.x + c.y) + (c.z + c.w)) + ((d.x + d.y) + (d.z + d.w));
}

// ---------------- K2 (dumb, verified) ----------------
// grid (32, 257); block (b,c): 8 lag-groups of 32 threads; group g computes
// tau = c*8+g via strided-t partial sums + width-32 shuffle reduce.
__global__ __launch_bounds__(256) void kautoc(const float* __restrict__ s,
                                              float* __restrict__ r) {
    __shared__ float ls[T_DIM];
    int b = blockIdx.x;
    const float* sb = s + (size_t)b * T_DIM;
    for (int i = threadIdx.x; i < T_DIM / 4; i += 256)
        ((float4*)ls)[i] = ((const float4*)sb)[i];
    __syncthreads();

    int tau = blockIdx.y * 8 + (threadIdx.x >> 5);
    int slice = threadIdx.x & 31;
    if (tau <= 2048) {
        float p = 0.0f;
        int tmax = T_DIM - tau;
        for (int t = slice; t < tmax; t += 32)
            p = fmaf(ls[t], ls[t + tau], p);
        for (int off = 16; off; off >>= 1)
            p += __shfl_down(p, off, 32);
        if (slice == 0)
            r[(size_t)b * NLAG + tau] = p;
    }
}

// ---------------- K3: planar output write ----------------
__global__ __launch_bounds__(256) void kdft(const float* __restrict__ r,
                                            float* __restrict__ out) {
    __shared__ float red[256];
    int b = blockIdx.x;
    int m = blockIdx.y;
    int tid = threadIdx.x;
    const float* rb = r + (size_t)b * NLAG;
    float part = 0.0f;
    for (int j = tid; j <= 2048; j += 256) {
        float wj = (j == 0 || j == 2048) ? 1.0f : 2.0f;
        int p = (m * j) & 4095;                       // exact integer phase
        part = fmaf(wj * rb[j], cosf((float)p * THETA), part);
    }
    red[tid] = part;
    __syncthreads();
    for (int sft = 128; sft; sft >>= 1) {
        if (tid < sft) red[tid] += red[tid + sft];
        __syncthreads();
    }
    if (tid == 0) {
        float A = red[0];
        int qp = (2047 * m) & 4095;
        float ang = (float)qp * THETA;
        float g = A * (1.0f / 16384.0f);              // 1/(256 pairs) * 1/sqrt(4096)
        // PLANAR layout: real plane [0..8191], imag plane [8192..16383]
        out[(size_t)b * 256 + m] = g * cosf(ang);
        out[8192 + (size_t)b * 256 + m] = -g * sinf(ang);
    }
}

// ---------------- Fallback: fully fused, zero workspace ----------------
__global__ __launch_bounds__(256) void kfused(const float* __restrict__ x,
                                              float* __restrict__ out) {
    __shared__ float ls[T_DIM];
    __shared__ float lr[NLAG];
    int b = blockIdx.x;
    int tid = threadIdx.x;
    for (int t = tid; t < T_DIM; t += 256) {
        const float4* xv = (const float4*)(x + ((size_t)b * T_DIM + t) * 16);
        float4 a = xv[0], bb = xv[1], c = xv[2], d = xv[3];
        ls[t] = ((a.x + a.y) + (a.z + a.w)) + ((bb.x + bb.y) + (bb.z + bb.w)) +
                ((c.x + c.y) + (c.z + c.w)) + ((d.x + d.y) + (d.z + d.w));
    }
    __syncthreads();
    for (int tau = tid; tau < NLAG; tau += 256) {
        float acc = 0.0f;
        int tmax = T_DIM - tau;
        for (int t = 0; t < tmax; ++t)
            acc = fmaf(ls[t], ls[t + tau], acc);
        lr[tau] = acc;
    }
    __syncthreads();
    int m = tid;                                      // 256 threads = 256 freqs
    float A = 0.0f;
    for (int j = 0; j <= 2048; ++j) {
        float wj = (j == 0 || j == 2048) ? 1.0f : 2.0f;
        int p = (m * j) & 4095;
        A = fmaf(wj * lr[j], cosf((float)p * THETA), A);
    }
    int qp = (2047 * m) & 4095;
    float ang = (float)qp * THETA;
    float g = A * (1.0f / 16384.0f);
    out[(size_t)b * 256 + m] = g * cosf(ang);
    out[8192 + (size_t)b * 256 + m] = -g * sinf(ang);
}

extern "C" void kernel_launch(void* const* d_in, const int* in_sizes, int n_in,
                              void* d_out, int out_size, void* d_ws, size_t ws_size,
                              hipStream_t stream) {
    const float* x = (const float*)d_in[0];
    float* out = (float*)d_out;
    size_t need = (size_t)(B_DIM * T_DIM + B_DIM * NLAG) * sizeof(float);
    if (ws_size >= need) {
        float* s = (float*)d_ws;                      // 32*4096 floats
        float* r = s + B_DIM * T_DIM;                 // 32*2049 floats
        ksum<<<dim3(512), dim3(256), 0, stream>>>(x, s);
        kautoc<<<dim3(B_DIM, 257), dim3(256), 0, stream>>>(s, r);
        kdft<<<dim3(B_DIM, 256), dim3(256), 0, stream>>>(r, out);
    } else {
        kfused<<<dim3(B_DIM), dim3(256), 0, stream>>>(x, out);
    }
}